// Round 2
// baseline (1442.091 us; speedup 1.0000x reference)
//
#include <hip/hip_runtime.h>

// RegionFeatureLearner: 16 region LSTMs (H=100) over T=2..6 steps, batch 32768,
// + 1-step backward LSTM. Forward recurrence via fp16 MFMA 16x16x32 in the
// "transposed" orientation G^T = W' @ [h|x|1]^T with gate-interleaved rows
// (N' = 4*j + gate) so each lane's 4 accumulator regs are the i,f,g,o gates of
// one (batch m, hidden j) -> gating + cell state fully in registers.
//
// R2: reverted R1's bwd fusion (bwd as separate kernel was only ~130 us; the
// fused epilogue cost +382 us). fwd restructured against its real bottleneck
// (barrier/latency serialization, not throughput): A-operand double-buffered
// in LDS -> ONE __syncthreads per step (was 2), and 64 batch rows per block
// (4 m-tiles, grid 8192) to halve per-row barrier cost and double W' reuse.
// Output staging overlays the A buffers (extra barrier in final step only).

typedef _Float16 f16;
typedef _Float16 half8 __attribute__((ext_vector_type(8)));
typedef float floatx4 __attribute__((ext_vector_type(4)));

#define FEAT_STRIDE 310   // 62*5 floats per batch item
#define AST 136           // A_lds row stride in halves (272 B, even bank spread)
#define ASZ (64 * AST)    // one A buffer: 64 rows
#define OST 104           // out-stage row stride in floats (16B-aligned rows)

__constant__ int c_pos[16][6] = {
 {3,0,1,2,4,0},{7,8,9,10,11,0},{5,6,0,0,0,0},{13,12,0,0,0,0},
 {14,15,23,24,32,33},{22,21,31,30,40,39},{16,17,18,19,20,0},{25,26,27,28,29,0},
 {34,35,36,37,38,0},{41,42,0,0,0,0},{49,48,0,0,0,0},{43,44,45,46,47,0},
 {50,51,57,0,0,0},{56,55,61,0,0,0},{52,53,54,0,0,0},{58,59,60,0,0,0}};
__constant__ int c_len[16] = {5,5,2,2,6,6,5,5,5,2,2,5,3,3,3,3};

__device__ __forceinline__ float sigf(float x) {
  return __builtin_amdgcn_rcpf(1.f + __builtin_amdgcn_exp2f(-1.44269504088896f * x));
}
__device__ __forceinline__ float tanhf_fast(float x) {
  // tanh(x) = 1 - 2/(exp(2x)+1)
  return 1.f - 2.f * __builtin_amdgcn_rcpf(1.f + __builtin_amdgcn_exp2f(2.88539008177793f * x));
}

// ---------------------------------------------------------------------------
// Prep: build W'[r][N'=4j+g][k] fp16, k: [0,100)=Whh row, [100,105)=Wih row,
// 105 = b_ih+b_hh, [106,128)=0.  Original gate row = g*100 + j (i,f,g,o chunks).
// ---------------------------------------------------------------------------
__global__ __launch_bounds__(256) void prep_kernel(
    const float* __restrict__ w_ih, const float* __restrict__ w_hh,
    const float* __restrict__ b_ih, const float* __restrict__ b_hh,
    f16* __restrict__ wp)
{
  int id = blockIdx.x * 256 + threadIdx.x;
  if (id >= 16 * 400 * 128) return;
  int k = id & 127;
  int rowN = (id >> 7) % 400;
  int r = (id >> 7) / 400;
  int j = rowN >> 2, g = rowN & 3;
  int orig = (r * 2 + 0) * 400 + g * 100 + j;   // forward direction (dir=0)
  float v;
  if (k < 100)       v = w_hh[orig * 100 + k];
  else if (k < 105)  v = w_ih[orig * 5 + (k - 100)];
  else if (k == 105) v = b_ih[orig] + b_hh[orig];
  else               v = 0.f;
  wp[id] = (f16)v;
}

// ---------------------------------------------------------------------------
// Forward: block = (region r, 64 batch rows). 320 threads = 5 waves, each wave
// owns 5 N'-tiles x 4 m-tiles (100 tiles x 4 kf = 400 MFMA/step/block).
// W' frags persist in VGPRs/AGPRs. A double-buffered in LDS: [m][k] halves,
// k in [0,128): h(0..99) x(100..104) 1(105) 0s.  One barrier per step.
// ---------------------------------------------------------------------------
__global__ __launch_bounds__(320, 3) void fwd_kernel(
    const float* __restrict__ feat, const f16* __restrict__ wp,
    float* __restrict__ out)
{
  // 2 x (64 x 136) halves = 34816 B; final-step fp32 out-stage overlays it.
  __shared__ __align__(16) f16 Abuf[2 * ASZ];
  float* smemf = (float*)Abuf;

  const int bx = blockIdx.x;
  const int r  = bx >> 9;               // 512 m-blocks per region
  const int n0 = (bx & 511) << 6;       // 64 batch rows per block
  const int tid  = threadIdx.x;
  const int wave = tid >> 6;
  const int lane = tid & 63;
  const int quad = lane >> 4;
  const int l15  = lane & 15;
  const int T = c_len[r];

  // ---- load W' fragments (persist): 5 tiles x 4 kfrags x 8 halves
  half8 wf[5][4];
  {
    const f16* wr = wp + (size_t)r * 400 * 128;
    #pragma unroll
    for (int tn = 0; tn < 5; ++tn) {
      int row = 16 * (5 * wave + tn) + l15;
      #pragma unroll
      for (int kf = 0; kf < 4; ++kf)
        wf[tn][kf] = *(const half8*)(wr + row * 128 + 32 * kf + 8 * quad);
    }
  }

  // ---- init both A buffers: h=0, x slots 0 (written below), k=105 -> 1.0
  // word index kw: 0..63 cover k 0..127 (2 halves/word); kw==52 -> halves
  // 104 (x slot, overwritten) / 105 (bias one).
  for (int i = tid; i < 2 * 64 * 64; i += 320) {
    int buf = i >> 12;
    int rem = i & 4095;
    int m = rem >> 6, kw = rem & 63;
    ((unsigned int*)Abuf)[buf * (ASZ / 2) + m * (AST / 2) + kw] =
        (kw == 52) ? 0x3C000000u : 0u;
  }

  // ---- preload all steps' x: 320 threads = 64 rows x 5 slots exactly
  float xv[6];
  const int xm = tid & 63, xs = tid >> 6;
  {
    const float* fb = feat + (size_t)(n0 + xm) * FEAT_STRIDE + xs;
    #pragma unroll
    for (int tt = 0; tt < 6; ++tt)
      if (tt < T) xv[tt] = fb[c_pos[r][tt] * 5];
  }
  __syncthreads();
  Abuf[xm * AST + 100 + xs] = (f16)xv[0];
  __syncthreads();

  float creg[4][5];
  #pragma unroll
  for (int mt = 0; mt < 4; ++mt)
    #pragma unroll
    for (int tn = 0; tn < 5; ++tn) creg[mt][tn] = 0.f;

  for (int t = 0; t < T; ++t) {
    const f16* Acur = Abuf + (t & 1) * ASZ;
    f16* Anxt = Abuf + ((t + 1) & 1) * ASZ;

    if (t + 1 < T) {
      #pragma unroll
      for (int mt = 0; mt < 4; ++mt) {
        half8 bf[4];
        #pragma unroll
        for (int kf = 0; kf < 4; ++kf)
          bf[kf] = *(const half8*)(Acur + (16 * mt + l15) * AST + 32 * kf + 8 * quad);
        #pragma unroll
        for (int tn = 0; tn < 5; ++tn) {
          floatx4 acc = {0.f, 0.f, 0.f, 0.f};
          #pragma unroll
          for (int kf = 0; kf < 4; ++kf)
            acc = __builtin_amdgcn_mfma_f32_16x16x32_f16(wf[tn][kf], bf[kf], acc, 0, 0, 0);
          float ig = sigf(acc[0]);
          float fg = sigf(acc[1]);
          float gg = tanhf_fast(acc[2]);
          float og = sigf(acc[3]);
          float cn = fg * creg[mt][tn] + ig * gg;
          creg[mt][tn] = cn;
          // write next-step h straight into the other buffer (no race: the
          // other buffer's reads all completed before the previous barrier)
          int j = 4 * (5 * wave + tn) + quad;
          Anxt[(16 * mt + l15) * AST + j] = (f16)(og * tanhf_fast(cn));
        }
      }
      Anxt[xm * AST + 100 + xs] = (f16)xv[t + 1];
      __syncthreads();   // next-step A complete; current-buffer reads done
    } else {
      // final step: pre-read ALL B-fragments, then drain reads before the
      // fp32 out-stage overlays the LDS.
      half8 bfa[4][4];
      #pragma unroll
      for (int mt = 0; mt < 4; ++mt)
        #pragma unroll
        for (int kf = 0; kf < 4; ++kf)
          bfa[mt][kf] = *(const half8*)(Acur + (16 * mt + l15) * AST + 32 * kf + 8 * quad);
      __syncthreads();   // all waves' reads of A complete
      #pragma unroll
      for (int mt = 0; mt < 4; ++mt) {
        #pragma unroll
        for (int tn = 0; tn < 5; ++tn) {
          floatx4 acc = {0.f, 0.f, 0.f, 0.f};
          #pragma unroll
          for (int kf = 0; kf < 4; ++kf)
            acc = __builtin_amdgcn_mfma_f32_16x16x32_f16(wf[tn][kf], bfa[mt][kf], acc, 0, 0, 0);
          float ig = sigf(acc[0]);
          float fg = sigf(acc[1]);
          float gg = tanhf_fast(acc[2]);
          float og = sigf(acc[3]);
          float cn = fg * creg[mt][tn] + ig * gg;
          int j = 4 * (5 * wave + tn) + quad;
          smemf[(16 * mt + l15) * OST + j] = og * tanhf_fast(cn);
        }
      }
      __syncthreads();   // out-stage complete
    }
  }

  // ---- coalesced output: out[n][r][0:100], 25 float4 per row, 64 rows
  #pragma unroll
  for (int it = 0; it < 5; ++it) {
    int idx = tid + it * 320;   // < 1600 always
    int m = idx / 25, ch = idx - m * 25;
    floatx4 v = *(const floatx4*)(smemf + m * OST + ch * 4);
    *(floatx4*)(out + (size_t)(n0 + m) * 3200 + r * 200 + ch * 4) = v;
  }
}

// ---------------------------------------------------------------------------
// Backward: single step with h0=c0=0 => g = x_last @ Wih_b^T + bias; f unused.
// Block = (region, 128 batch rows); weights (i,g,o rows only) staged in LDS.
// ---------------------------------------------------------------------------
__global__ __launch_bounds__(256) void bwd_kernel(
    const float* __restrict__ feat, const float* __restrict__ w_ih,
    const float* __restrict__ b_ih, const float* __restrict__ b_hh,
    float* __restrict__ out)
{
  __shared__ float wg[300 * 7];   // rows: i(0..99) g(100..199) o(200..299); [w0..w4,bias,pad]
  __shared__ float xs[128 * 5];
  const int bx = blockIdx.x;
  const int r  = bx >> 8;          // 256 n-chunks per region
  const int n0 = (bx & 255) << 7;  // 128 rows per block
  const int tid = threadIdx.x;
  const int pos = c_pos[r][c_len[r] - 1];

  for (int i = tid; i < 2100; i += 256) {
    int row = i / 7, c = i - row * 7;
    int q = row / 100, jj = row - q * 100;
    int qq = (q == 0) ? 0 : (q + 1);            // 0->i, 1->g(2), 2->o(3)
    int orig = (r * 2 + 1) * 400 + qq * 100 + jj;  // backward direction (dir=1)
    float v = 0.f;
    if (c < 5)       v = w_ih[orig * 5 + c];
    else if (c == 5) v = b_ih[orig] + b_hh[orig];
    wg[i] = v;
  }
  for (int i = tid; i < 640; i += 256) {
    int nl = i / 5, s = i - nl * 5;
    xs[i] = feat[(size_t)(n0 + nl) * FEAT_STRIDE + pos * 5 + s];
  }
  __syncthreads();

  for (int idx = tid; idx < 12800; idx += 256) {
    int nl = idx / 100, jj = idx - nl * 100;
    const float* xp = xs + nl * 5;
    float x0 = xp[0], x1 = xp[1], x2 = xp[2], x3 = xp[3], x4 = xp[4];
    const float* wi = wg + jj * 7;
    const float* wc = wg + (100 + jj) * 7;
    const float* wo = wg + (200 + jj) * 7;
    float gi = wi[5] + wi[0]*x0 + wi[1]*x1 + wi[2]*x2 + wi[3]*x3 + wi[4]*x4;
    float gc = wc[5] + wc[0]*x0 + wc[1]*x1 + wc[2]*x2 + wc[3]*x3 + wc[4]*x4;
    float go = wo[5] + wo[0]*x0 + wo[1]*x1 + wo[2]*x2 + wo[3]*x3 + wo[4]*x4;
    float c = sigf(gi) * tanhf_fast(gc);
    float h = sigf(go) * tanhf_fast(c);
    out[(size_t)(n0 + nl) * 3200 + r * 200 + 100 + jj] = h;
  }
}

extern "C" void kernel_launch(void* const* d_in, const int* in_sizes, int n_in,
                              void* d_out, int out_size, void* d_ws, size_t ws_size,
                              hipStream_t stream) {
  const float* feat = (const float*)d_in[0];
  const float* w_ih = (const float*)d_in[1];
  const float* w_hh = (const float*)d_in[2];
  const float* b_ih = (const float*)d_in[3];
  const float* b_hh = (const float*)d_in[4];
  float* out = (float*)d_out;
  f16* wp = (f16*)d_ws;   // 16*400*128*2 = 1.64 MB

  prep_kernel<<<3200, 256, 0, stream>>>(w_ih, w_hh, b_ih, b_hh, wp);
  fwd_kernel<<<8192, 320, 0, stream>>>(feat, wp, out);
  bwd_kernel<<<4096, 256, 0, stream>>>(feat, w_ih, b_ih, b_hh, out);
}

// Round 3
// 1082.300 us; speedup vs baseline: 1.3324x; 1.3324x over previous
//
#include <hip/hip_runtime.h>

// RegionFeatureLearner: 16 region LSTMs (H=100) over T=2..6 steps, batch 32768,
// + 1-step backward LSTM. Forward recurrence via fp16 MFMA 16x16x32 in the
// "transposed" orientation G^T = W' @ [h|x|1]^T with gate-interleaved rows
// (N' = 4*j + gate) so each lane's 4 accumulator regs are the i,f,g,o gates of
// one (batch m, hidden j) -> gating + cell state fully in registers.
//
// R3: R2's 64-row/1-barrier structure, spill fixed. R2 spilled ~790 MB of
// scratch (WRITE_SIZE 999 MB) because the final-step bfa[4][4] pre-read added
// 64 live VGPRs past the launch_bounds(320,3) cap of ~170. Final step now
// computes hreg[4][5] (20 regs) and re-syncs before overlaying LDS with the
// fp32 out-stage. bwd reworked: one thread per jj keeps its 18 weights in
// registers and loops 64 batch rows (LDS reads ~1150 -> ~340 per thread).

typedef _Float16 f16;
typedef _Float16 half8 __attribute__((ext_vector_type(8)));
typedef float floatx4 __attribute__((ext_vector_type(4)));

#define FEAT_STRIDE 310   // 62*5 floats per batch item
#define AST 136           // A_lds row stride in halves (272 B, even bank spread)
#define ASZ (64 * AST)    // one A buffer: 64 rows
#define OST 104           // out-stage row stride in floats (16B-aligned rows)

__constant__ int c_pos[16][6] = {
 {3,0,1,2,4,0},{7,8,9,10,11,0},{5,6,0,0,0,0},{13,12,0,0,0,0},
 {14,15,23,24,32,33},{22,21,31,30,40,39},{16,17,18,19,20,0},{25,26,27,28,29,0},
 {34,35,36,37,38,0},{41,42,0,0,0,0},{49,48,0,0,0,0},{43,44,45,46,47,0},
 {50,51,57,0,0,0},{56,55,61,0,0,0},{52,53,54,0,0,0},{58,59,60,0,0,0}};
__constant__ int c_len[16] = {5,5,2,2,6,6,5,5,5,2,2,5,3,3,3,3};

__device__ __forceinline__ float sigf(float x) {
  return __builtin_amdgcn_rcpf(1.f + __builtin_amdgcn_exp2f(-1.44269504088896f * x));
}
__device__ __forceinline__ float tanhf_fast(float x) {
  // tanh(x) = 1 - 2/(exp(2x)+1)
  return 1.f - 2.f * __builtin_amdgcn_rcpf(1.f + __builtin_amdgcn_exp2f(2.88539008177793f * x));
}

// ---------------------------------------------------------------------------
// Prep: build W'[r][N'=4j+g][k] fp16, k: [0,100)=Whh row, [100,105)=Wih row,
// 105 = b_ih+b_hh, [106,128)=0.  Original gate row = g*100 + j (i,f,g,o chunks).
// ---------------------------------------------------------------------------
__global__ __launch_bounds__(256) void prep_kernel(
    const float* __restrict__ w_ih, const float* __restrict__ w_hh,
    const float* __restrict__ b_ih, const float* __restrict__ b_hh,
    f16* __restrict__ wp)
{
  int id = blockIdx.x * 256 + threadIdx.x;
  if (id >= 16 * 400 * 128) return;
  int k = id & 127;
  int rowN = (id >> 7) % 400;
  int r = (id >> 7) / 400;
  int j = rowN >> 2, g = rowN & 3;
  int orig = (r * 2 + 0) * 400 + g * 100 + j;   // forward direction (dir=0)
  float v;
  if (k < 100)       v = w_hh[orig * 100 + k];
  else if (k < 105)  v = w_ih[orig * 5 + (k - 100)];
  else if (k == 105) v = b_ih[orig] + b_hh[orig];
  else               v = 0.f;
  wp[id] = (f16)v;
}

// ---------------------------------------------------------------------------
// Forward: block = (region r, 64 batch rows). 320 threads = 5 waves, each wave
// owns 5 N'-tiles x 4 m-tiles (100 tiles x 4 kf = 400 MFMA/step/block).
// W' frags persist in VGPRs/AGPRs. A double-buffered in LDS: [m][k] halves,
// k in [0,128): h(0..99) x(100..104) 1(105) 0s.  One barrier per step.
// ---------------------------------------------------------------------------
__global__ __launch_bounds__(320, 3) void fwd_kernel(
    const float* __restrict__ feat, const f16* __restrict__ wp,
    float* __restrict__ out)
{
  // 2 x (64 x 136) halves = 34816 B; final-step fp32 out-stage overlays it.
  __shared__ __align__(16) f16 Abuf[2 * ASZ];
  float* smemf = (float*)Abuf;

  const int bx = blockIdx.x;
  const int r  = bx >> 9;               // 512 m-blocks per region
  const int n0 = (bx & 511) << 6;       // 64 batch rows per block
  const int tid  = threadIdx.x;
  const int wave = tid >> 6;
  const int lane = tid & 63;
  const int quad = lane >> 4;
  const int l15  = lane & 15;
  const int T = c_len[r];

  // ---- load W' fragments (persist): 5 tiles x 4 kfrags x 8 halves
  half8 wf[5][4];
  {
    const f16* wr = wp + (size_t)r * 400 * 128;
    #pragma unroll
    for (int tn = 0; tn < 5; ++tn) {
      int row = 16 * (5 * wave + tn) + l15;
      #pragma unroll
      for (int kf = 0; kf < 4; ++kf)
        wf[tn][kf] = *(const half8*)(wr + row * 128 + 32 * kf + 8 * quad);
    }
  }

  // ---- init both A buffers: h=0, x slots 0 (written below), k=105 -> 1.0
  // word index kw: 0..63 cover k 0..127 (2 halves/word); kw==52 -> halves
  // 104 (x slot, overwritten) / 105 (bias one).
  for (int i = tid; i < 2 * 64 * 64; i += 320) {
    int buf = i >> 12;
    int rem = i & 4095;
    int m = rem >> 6, kw = rem & 63;
    ((unsigned int*)Abuf)[buf * (ASZ / 2) + m * (AST / 2) + kw] =
        (kw == 52) ? 0x3C000000u : 0u;
  }

  // ---- preload all steps' x: 320 threads = 64 rows x 5 slots exactly
  float xv[6];
  const int xm = tid & 63, xs = tid >> 6;
  {
    const float* fb = feat + (size_t)(n0 + xm) * FEAT_STRIDE + xs;
    #pragma unroll
    for (int tt = 0; tt < 6; ++tt)
      if (tt < T) xv[tt] = fb[c_pos[r][tt] * 5];
  }
  __syncthreads();
  Abuf[xm * AST + 100 + xs] = (f16)xv[0];
  __syncthreads();

  float creg[4][5];
  #pragma unroll
  for (int mt = 0; mt < 4; ++mt)
    #pragma unroll
    for (int tn = 0; tn < 5; ++tn) creg[mt][tn] = 0.f;

  for (int t = 0; t < T; ++t) {
    const f16* Acur = Abuf + (t & 1) * ASZ;
    f16* Anxt = Abuf + ((t + 1) & 1) * ASZ;

    if (t + 1 < T) {
      #pragma unroll
      for (int mt = 0; mt < 4; ++mt) {
        half8 bf[4];
        #pragma unroll
        for (int kf = 0; kf < 4; ++kf)
          bf[kf] = *(const half8*)(Acur + (16 * mt + l15) * AST + 32 * kf + 8 * quad);
        #pragma unroll
        for (int tn = 0; tn < 5; ++tn) {
          floatx4 acc = {0.f, 0.f, 0.f, 0.f};
          #pragma unroll
          for (int kf = 0; kf < 4; ++kf)
            acc = __builtin_amdgcn_mfma_f32_16x16x32_f16(wf[tn][kf], bf[kf], acc, 0, 0, 0);
          float ig = sigf(acc[0]);
          float fg = sigf(acc[1]);
          float gg = tanhf_fast(acc[2]);
          float og = sigf(acc[3]);
          float cn = fg * creg[mt][tn] + ig * gg;
          creg[mt][tn] = cn;
          // write next-step h straight into the other buffer (no race: that
          // buffer's reads all completed before the previous barrier)
          int j = 4 * (5 * wave + tn) + quad;
          Anxt[(16 * mt + l15) * AST + j] = (f16)(og * tanhf_fast(cn));
        }
      }
      Anxt[xm * AST + 100 + xs] = (f16)xv[t + 1];
      __syncthreads();   // next-step A complete; current-buffer reads done
    } else {
      // final step: keep h in registers (20 VGPRs, NOT a 64-reg fragment
      // pre-read -> no spill), drain all reads, then overlay fp32 out-stage.
      float hreg[4][5];
      #pragma unroll
      for (int mt = 0; mt < 4; ++mt) {
        half8 bf[4];
        #pragma unroll
        for (int kf = 0; kf < 4; ++kf)
          bf[kf] = *(const half8*)(Acur + (16 * mt + l15) * AST + 32 * kf + 8 * quad);
        #pragma unroll
        for (int tn = 0; tn < 5; ++tn) {
          floatx4 acc = {0.f, 0.f, 0.f, 0.f};
          #pragma unroll
          for (int kf = 0; kf < 4; ++kf)
            acc = __builtin_amdgcn_mfma_f32_16x16x32_f16(wf[tn][kf], bf[kf], acc, 0, 0, 0);
          float ig = sigf(acc[0]);
          float fg = sigf(acc[1]);
          float gg = tanhf_fast(acc[2]);
          float og = sigf(acc[3]);
          float cn = fg * creg[mt][tn] + ig * gg;
          hreg[mt][tn] = og * tanhf_fast(cn);
        }
      }
      __syncthreads();   // all waves' reads of A complete
      #pragma unroll
      for (int mt = 0; mt < 4; ++mt)
        #pragma unroll
        for (int tn = 0; tn < 5; ++tn) {
          int j = 4 * (5 * wave + tn) + quad;
          smemf[(16 * mt + l15) * OST + j] = hreg[mt][tn];
        }
      __syncthreads();   // out-stage complete
    }
  }

  // ---- coalesced output: out[n][r][0:100], 25 float4 per row, 64 rows
  #pragma unroll
  for (int it = 0; it < 5; ++it) {
    int idx = tid + it * 320;   // < 1600 always
    int m = idx / 25, ch = idx - m * 25;
    floatx4 v = *(const floatx4*)(smemf + m * OST + ch * 4);
    *(floatx4*)(out + (size_t)(n0 + m) * 3200 + r * 200 + ch * 4) = v;
  }
}

// ---------------------------------------------------------------------------
// Backward: single step with h0=c0=0 => g = x_last @ Wih_b^T + bias; f unused.
// Block = (region, 128 batch rows). Threads 0..199: thread owns one jj
// (weights in 18 registers) and loops 64 batch rows.
// ---------------------------------------------------------------------------
__global__ __launch_bounds__(256) void bwd_kernel(
    const float* __restrict__ feat, const float* __restrict__ w_ih,
    const float* __restrict__ b_ih, const float* __restrict__ b_hh,
    float* __restrict__ out)
{
  __shared__ float wg[300 * 7];   // rows: i(0..99) g(100..199) o(200..299); [w0..w4,bias,pad]
  __shared__ float xs[128 * 5];
  const int bx = blockIdx.x;
  const int r  = bx >> 8;          // 256 n-chunks per region
  const int n0 = (bx & 255) << 7;  // 128 rows per block
  const int tid = threadIdx.x;
  const int pos = c_pos[r][c_len[r] - 1];

  for (int i = tid; i < 2100; i += 256) {
    int row = i / 7, c = i - row * 7;
    int q = row / 100, jj = row - q * 100;
    int qq = (q == 0) ? 0 : (q + 1);            // 0->i, 1->g(2), 2->o(3)
    int orig = (r * 2 + 1) * 400 + qq * 100 + jj;  // backward direction (dir=1)
    float v = 0.f;
    if (c < 5)       v = w_ih[orig * 5 + c];
    else if (c == 5) v = b_ih[orig] + b_hh[orig];
    wg[i] = v;
  }
  for (int i = tid; i < 640; i += 256) {
    int nl = i / 5, s = i - nl * 5;
    xs[i] = feat[(size_t)(n0 + nl) * FEAT_STRIDE + pos * 5 + s];
  }
  __syncthreads();

  if (tid < 200) {
    const int g  = tid / 100;        // which 64-row half
    const int jj = tid - g * 100;
    const float* wi = wg + jj * 7;
    const float* wc = wg + (100 + jj) * 7;
    const float* wo = wg + (200 + jj) * 7;
    float i0 = wi[0], i1 = wi[1], i2 = wi[2], i3 = wi[3], i4 = wi[4], ib = wi[5];
    float c0 = wc[0], c1 = wc[1], c2 = wc[2], c3 = wc[3], c4 = wc[4], cb = wc[5];
    float o0 = wo[0], o1 = wo[1], o2 = wo[2], o3 = wo[3], o4 = wo[4], ob = wo[5];
    for (int i = 0; i < 64; ++i) {
      int nl = g * 64 + i;
      const float* xp = xs + nl * 5;
      float x0 = xp[0], x1 = xp[1], x2 = xp[2], x3 = xp[3], x4 = xp[4];
      float gi = ib + i0*x0 + i1*x1 + i2*x2 + i3*x3 + i4*x4;
      float gc = cb + c0*x0 + c1*x1 + c2*x2 + c3*x3 + c4*x4;
      float go = ob + o0*x0 + o1*x1 + o2*x2 + o3*x3 + o4*x4;
      float cc = sigf(gi) * tanhf_fast(gc);
      float hh = sigf(go) * tanhf_fast(cc);
      out[(size_t)(n0 + nl) * 3200 + r * 200 + 100 + jj] = hh;
    }
  }
}

extern "C" void kernel_launch(void* const* d_in, const int* in_sizes, int n_in,
                              void* d_out, int out_size, void* d_ws, size_t ws_size,
                              hipStream_t stream) {
  const float* feat = (const float*)d_in[0];
  const float* w_ih = (const float*)d_in[1];
  const float* w_hh = (const float*)d_in[2];
  const float* b_ih = (const float*)d_in[3];
  const float* b_hh = (const float*)d_in[4];
  float* out = (float*)d_out;
  f16* wp = (f16*)d_ws;   // 16*400*128*2 = 1.64 MB

  prep_kernel<<<3200, 256, 0, stream>>>(w_ih, w_hh, b_ih, b_hh, wp);
  fwd_kernel<<<8192, 320, 0, stream>>>(feat, wp, out);
  bwd_kernel<<<4096, 256, 0, stream>>>(feat, w_ih, b_ih, b_hh, out);
}

// Round 4
// 947.711 us; speedup vs baseline: 1.5217x; 1.1420x over previous
//
#include <hip/hip_runtime.h>

// RegionFeatureLearner: 16 region LSTMs (H=100) over T=2..6 steps, batch 32768,
// + 1-step backward LSTM.
//
// R4: barrier-free forward recurrence. Each wave owns 16 batch rows and
// computes ALL 400 gate rows (25 MFMA N'-tiles), so h never crosses waves:
// the T-step loop has ZERO __syncthreads (wave-private LDS scratch, hardware
// lgkmcnt ordering only; in-place h update is safe because B-frags are in
// registers before any h write). W' (400x128 f16) is staged once per block
// into LDS (108.8 KB) and re-read per step (100 ds_read_b128/wave/step,
// stride 136 halves -> 2-way bank spread). x staged in LDS (kills the
// dynamic-index xv scratch spill seen in R3: WRITE 254 vs 213 MB ideal).
// Block = 8 waves x 16 rows = 128 rows, grid 4096, LDS 158976 B -> 1
// block/CU (2 free-running waves/SIMD). Final h written straight to global.

typedef _Float16 f16;
typedef _Float16 half8 __attribute__((ext_vector_type(8)));
typedef float floatx4 __attribute__((ext_vector_type(4)));

#define FEAT_STRIDE 310   // 62*5 floats per batch item
#define WST 136           // W'/scratch row stride in halves (272 B -> 2-way banks)

__constant__ int c_pos[16][6] = {
 {3,0,1,2,4,0},{7,8,9,10,11,0},{5,6,0,0,0,0},{13,12,0,0,0,0},
 {14,15,23,24,32,33},{22,21,31,30,40,39},{16,17,18,19,20,0},{25,26,27,28,29,0},
 {34,35,36,37,38,0},{41,42,0,0,0,0},{49,48,0,0,0,0},{43,44,45,46,47,0},
 {50,51,57,0,0,0},{56,55,61,0,0,0},{52,53,54,0,0,0},{58,59,60,0,0,0}};
__constant__ int c_len[16] = {5,5,2,2,6,6,5,5,5,2,2,5,3,3,3,3};

__device__ __forceinline__ float sigf(float x) {
  return __builtin_amdgcn_rcpf(1.f + __builtin_amdgcn_exp2f(-1.44269504088896f * x));
}
__device__ __forceinline__ float tanhf_fast(float x) {
  // tanh(x) = 1 - 2/(exp(2x)+1)
  return 1.f - 2.f * __builtin_amdgcn_rcpf(1.f + __builtin_amdgcn_exp2f(2.88539008177793f * x));
}

// ---------------------------------------------------------------------------
// Prep: build W'[r][N'=4j+g][k] fp16, k: [0,100)=Whh row, [100,105)=Wih row,
// 105 = b_ih+b_hh, [106,128)=0.  Original gate row = g*100 + j (i,f,g,o chunks).
// ---------------------------------------------------------------------------
__global__ __launch_bounds__(256) void prep_kernel(
    const float* __restrict__ w_ih, const float* __restrict__ w_hh,
    const float* __restrict__ b_ih, const float* __restrict__ b_hh,
    f16* __restrict__ wp)
{
  int id = blockIdx.x * 256 + threadIdx.x;
  if (id >= 16 * 400 * 128) return;
  int k = id & 127;
  int rowN = (id >> 7) % 400;
  int r = (id >> 7) / 400;
  int j = rowN >> 2, g = rowN & 3;
  int orig = (r * 2 + 0) * 400 + g * 100 + j;   // forward direction (dir=0)
  float v;
  if (k < 100)       v = w_hh[orig * 100 + k];
  else if (k < 105)  v = w_ih[orig * 5 + (k - 100)];
  else if (k == 105) v = b_ih[orig] + b_hh[orig];
  else               v = 0.f;
  wp[id] = (f16)v;
}

// ---------------------------------------------------------------------------
// Forward: block = (region r, 128 batch rows) = 8 waves x 16 rows.
// LDS: W' [400][WST] f16 (108800 B) | scratch [8][16][WST] f16 (34816 B)
//    | x [T][128][5] f32 (15360 B)  -> 158976 B total.
// Scratch row k-layout: h(0..99) x(100..104) 1(105) 0(106..127).
// ---------------------------------------------------------------------------
__global__ __launch_bounds__(512, 2) void fwd_kernel(
    const float* __restrict__ feat, const f16* __restrict__ wp,
    float* __restrict__ out)
{
  __shared__ __align__(16) unsigned char lds_raw[158976];
  f16*   Wl = (f16*)lds_raw;                       // [400][WST]
  f16*   Sl = (f16*)(lds_raw + 108800);            // [8][16][WST]
  float* Xl = (float*)(lds_raw + 143616);          // [T][128][5]

  const int bx = blockIdx.x;
  const int r  = bx >> 8;               // 256 m-blocks per region
  const int n0 = (bx & 255) << 7;       // 128 batch rows per block
  const int tid  = threadIdx.x;
  const int wave = tid >> 6;
  const int lane = tid & 63;
  const int quad = lane >> 4;
  const int l15  = lane & 15;
  const int T = c_len[r];

  // ---- stage W' -> LDS (fully coalesced 16B chunks)
  {
    const f16* wr = wp + (size_t)r * 400 * 128;
    for (int idx = tid; idx < 400 * 16; idx += 512) {
      int row = idx >> 4, c = idx & 15;
      *(half8*)(Wl + row * WST + 8 * c) = *(const half8*)(wr + row * 128 + 8 * c);
    }
  }
  // ---- stage all steps' x -> LDS
  for (int idx = tid; idx < T * 640; idx += 512) {
    int t = idx / 640, rem = idx - t * 640;
    int m = rem / 5, s = rem - m * 5;
    Xl[idx] = feat[(size_t)(n0 + m) * FEAT_STRIDE + c_pos[r][t] * 5 + s];
  }
  // ---- init scratch: zeros, k=105 -> 1.0f16 (word 52: lo=x-slot104, hi=105)
  {
    unsigned int* Swd = (unsigned int*)Sl;
    for (int idx = tid; idx < 8 * 16 * (WST / 2); idx += 512) {
      int kw = idx % (WST / 2);
      Swd[idx] = (kw == 52) ? 0x3C000000u : 0u;
    }
  }
  __syncthreads();   // the ONLY block-wide barrier

  f16* Sw = Sl + wave * 16 * WST;       // this wave's private scratch
  const int xm = lane >> 2, xsl = lane & 3;   // 64 lanes = 16 rows x slots 0..3

  float creg[25];
  #pragma unroll
  for (int tn = 0; tn < 25; ++tn) creg[tn] = 0.f;

  for (int t = 0; t < T; ++t) {
    // write this step's x into scratch (h slots hold h_{t-1} / zeros)
    Sw[xm * WST + 100 + xsl] = (f16)Xl[t * 640 + (wave * 16 + xm) * 5 + xsl];
    if (lane < 16)
      Sw[l15 * WST + 104] = (f16)Xl[t * 640 + (wave * 16 + l15) * 5 + 4];

    // B-frags into registers BEFORE any h write -> in-place update is safe
    half8 bf[4];
    #pragma unroll
    for (int kf = 0; kf < 4; ++kf)
      bf[kf] = *(const half8*)(Sw + l15 * WST + 32 * kf + 8 * quad);

    const bool last = (t + 1 == T);
    #pragma unroll
    for (int tn = 0; tn < 25; ++tn) {
      floatx4 acc = {0.f, 0.f, 0.f, 0.f};
      #pragma unroll
      for (int kf = 0; kf < 4; ++kf) {
        half8 wfr = *(const half8*)(Wl + (16 * tn + l15) * WST + 32 * kf + 8 * quad);
        acc = __builtin_amdgcn_mfma_f32_16x16x32_f16(wfr, bf[kf], acc, 0, 0, 0);
      }
      // lane holds gates i,f,g,o of (m = n0+16*wave+l15, j = 4*tn+quad)
      float ig = sigf(acc[0]);
      float fg = sigf(acc[1]);
      float gg = tanhf_fast(acc[2]);
      float og = sigf(acc[3]);
      float cn = fg * creg[tn] + ig * gg;
      creg[tn] = cn;
      float hv = og * tanhf_fast(cn);
      int j = 4 * tn + quad;
      if (!last) {
        Sw[l15 * WST + j] = (f16)hv;   // wave-local; no barrier needed
      } else {
        // 4 quads x consecutive j -> 16B contiguous per row
        out[(size_t)(n0 + wave * 16 + l15) * 3200 + r * 200 + j] = hv;
      }
    }
  }
}

// ---------------------------------------------------------------------------
// Backward: single step with h0=c0=0 => g = x_last @ Wih_b^T + bias; f unused.
// Block = (region, 128 batch rows). Threads 0..199: thread owns one jj
// (weights in 18 registers) and loops 64 batch rows.
// ---------------------------------------------------------------------------
__global__ __launch_bounds__(256) void bwd_kernel(
    const float* __restrict__ feat, const float* __restrict__ w_ih,
    const float* __restrict__ b_ih, const float* __restrict__ b_hh,
    float* __restrict__ out)
{
  __shared__ float wg[300 * 7];   // rows: i(0..99) g(100..199) o(200..299); [w0..w4,bias,pad]
  __shared__ float xs[128 * 5];
  const int bx = blockIdx.x;
  const int r  = bx >> 8;          // 256 n-chunks per region
  const int n0 = (bx & 255) << 7;  // 128 rows per block
  const int tid = threadIdx.x;
  const int pos = c_pos[r][c_len[r] - 1];

  for (int i = tid; i < 2100; i += 256) {
    int row = i / 7, c = i - row * 7;
    int q = row / 100, jj = row - q * 100;
    int qq = (q == 0) ? 0 : (q + 1);            // 0->i, 1->g(2), 2->o(3)
    int orig = (r * 2 + 1) * 400 + qq * 100 + jj;  // backward direction (dir=1)
    float v = 0.f;
    if (c < 5)       v = w_ih[orig * 5 + c];
    else if (c == 5) v = b_ih[orig] + b_hh[orig];
    wg[i] = v;
  }
  for (int i = tid; i < 640; i += 256) {
    int nl = i / 5, s = i - nl * 5;
    xs[i] = feat[(size_t)(n0 + nl) * FEAT_STRIDE + pos * 5 + s];
  }
  __syncthreads();

  if (tid < 200) {
    const int g  = tid / 100;        // which 64-row half
    const int jj = tid - g * 100;
    const float* wi = wg + jj * 7;
    const float* wc = wg + (100 + jj) * 7;
    const float* wo = wg + (200 + jj) * 7;
    float i0 = wi[0], i1 = wi[1], i2 = wi[2], i3 = wi[3], i4 = wi[4], ib = wi[5];
    float c0 = wc[0], c1 = wc[1], c2 = wc[2], c3 = wc[3], c4 = wc[4], cb = wc[5];
    float o0 = wo[0], o1 = wo[1], o2 = wo[2], o3 = wo[3], o4 = wo[4], ob = wo[5];
    for (int i = 0; i < 64; ++i) {
      int nl = g * 64 + i;
      const float* xp = xs + nl * 5;
      float x0 = xp[0], x1 = xp[1], x2 = xp[2], x3 = xp[3], x4 = xp[4];
      float gi = ib + i0*x0 + i1*x1 + i2*x2 + i3*x3 + i4*x4;
      float gc = cb + c0*x0 + c1*x1 + c2*x2 + c3*x3 + c4*x4;
      float go = ob + o0*x0 + o1*x1 + o2*x2 + o3*x3 + o4*x4;
      float cc = sigf(gi) * tanhf_fast(gc);
      float hh = sigf(go) * tanhf_fast(cc);
      out[(size_t)(n0 + nl) * 3200 + r * 200 + 100 + jj] = hh;
    }
  }
}

extern "C" void kernel_launch(void* const* d_in, const int* in_sizes, int n_in,
                              void* d_out, int out_size, void* d_ws, size_t ws_size,
                              hipStream_t stream) {
  const float* feat = (const float*)d_in[0];
  const float* w_ih = (const float*)d_in[1];
  const float* w_hh = (const float*)d_in[2];
  const float* b_ih = (const float*)d_in[3];
  const float* b_hh = (const float*)d_in[4];
  float* out = (float*)d_out;
  f16* wp = (f16*)d_ws;   // 16*400*128*2 = 1.64 MB

  prep_kernel<<<3200, 256, 0, stream>>>(w_ih, w_hh, b_ih, b_hh, wp);
  fwd_kernel<<<4096, 512, 0, stream>>>(feat, wp, out);
  bwd_kernel<<<4096, 256, 0, stream>>>(feat, w_ih, b_ih, b_hh, out);
}